// Round 1
// 1059.972 us; speedup vs baseline: 1.1284x; 1.1284x over previous
//
#include <hip/hip_runtime.h>
#include <stdint.h>

typedef __bf16 bf16;
typedef unsigned short u16;
typedef __bf16  bf16x8 __attribute__((ext_vector_type(8)));
typedef unsigned short u16x8 __attribute__((ext_vector_type(8)));
typedef unsigned short u16x4 __attribute__((ext_vector_type(4)));
typedef float   f32x4  __attribute__((ext_vector_type(4)));

typedef __attribute__((address_space(1))) uint32_t gu32;
typedef __attribute__((address_space(3))) uint32_t su32;

__device__ __forceinline__ void async_cp16(const void* gp, void* sp) {
    // 16B per lane, LDS dest = wave-uniform base + lane*16 (m97/m104 semantics)
    __builtin_amdgcn_global_load_lds((const gu32*)gp, (su32*)sp, 16, 0, 0);
}

// ---------------------------------------------------------------------------
// Detect input dtype from bit patterns of q. bf16 N(0,1): ~all u16 words have
// exponent field in [96,160). f32 read as u16 pairs: high halves yes (~2048),
// low halves ~25% (~512) => ~2560. Threshold 3500. flag=1 means f32 inputs.
// ---------------------------------------------------------------------------
__global__ void detect_dtype(const u16* __restrict__ q, int* __restrict__ flag)
{
    __shared__ int cnt;
    if (threadIdx.x == 0) cnt = 0;
    __syncthreads();
    int c = 0;
    for (int i = threadIdx.x; i < 4096; i += 64) {
        const int e = (q[i] >> 7) & 0xFF;
        if (e >= 96 && e < 160) c++;
    }
    atomicAdd(&cnt, c);
    __syncthreads();
    if (threadIdx.x == 0) *flag = (cnt < 3500) ? 1 : 0;
}

// ---------------------------------------------------------------------------
// Convert input tensor (f32 or bf16 per flag) to bf16. 8 elems/thread.
// ---------------------------------------------------------------------------
__global__ __launch_bounds__(256) void convert_in(
    const void* __restrict__ src, bf16* __restrict__ dst, int n,
    const int* __restrict__ flagp)
{
    const bool srcF32 = (*flagp != 0);
    const int idx = blockIdx.x * 256 + threadIdx.x;
    if (idx * 8 >= n) return;
    bf16x8 v;
    if (srcF32) {
        const float4 a = ((const float4*)src)[idx * 2];
        const float4 b = ((const float4*)src)[idx * 2 + 1];
        v[0] = (bf16)a.x; v[1] = (bf16)a.y; v[2] = (bf16)a.z; v[3] = (bf16)a.w;
        v[4] = (bf16)b.x; v[5] = (bf16)b.y; v[6] = (bf16)b.z; v[7] = (bf16)b.w;
    } else {
        v = ((const bf16x8*)src)[idx];
    }
    ((bf16x8*)dst)[idx] = v;
}

// ---------------------------------------------------------------------------
// All four 1024-elem biases in one launch. 256 threads, 4 elems per tensor.
// ---------------------------------------------------------------------------
__global__ __launch_bounds__(256) void convert_bias4(
    const void* __restrict__ b0, const void* __restrict__ b1,
    const void* __restrict__ b2, const void* __restrict__ b3,
    bf16* __restrict__ dst, const int* __restrict__ flagp)
{
    const bool srcF32 = (*flagp != 0);
    const int tid = threadIdx.x;
    const void* srcs[4] = {b0, b1, b2, b3};
#pragma unroll
    for (int t = 0; t < 4; t++) {
        bf16* d = dst + t * 2048 + tid * 4;
        if (srcF32) {
            const float4 v = ((const float4*)srcs[t])[tid];
            d[0] = (bf16)v.x; d[1] = (bf16)v.y; d[2] = (bf16)v.z; d[3] = (bf16)v.w;
        } else {
            *(u16x4*)d = *((const u16x4*)srcs[t] + tid);
        }
    }
}

// ---------------------------------------------------------------------------
// Generic C = A @ B^T + bias GEMM, bf16 in, f32 accumulate.
// Output bf16, or f32 when (flagp && *flagp). m97 structure, 128x128, BK=32.
// ---------------------------------------------------------------------------
__global__ __launch_bounds__(256) void gemm_bt128(
    const bf16* __restrict__ A, const bf16* __restrict__ BT,
    const bf16* __restrict__ bias, void* __restrict__ C,
    int M, int N, int K, const int* __restrict__ flagp)
{
    __shared__ alignas(16) bf16 As[128 * 32];
    __shared__ alignas(16) bf16 Bs[128 * 32];
    const bool outF32 = flagp && (*flagp != 0);
    const int tid  = threadIdx.x;
    const int lane = tid & 63, wave = tid >> 6;
    const int l16  = lane & 15, quad = lane >> 4;
    const int m0   = blockIdx.y * 128, n0 = blockIdx.x * 128;
    const int wm   = (wave >> 1) * 64, wn = (wave & 1) * 64;

    f32x4 acc[4][4];
#pragma unroll
    for (int i = 0; i < 4; i++)
#pragma unroll
        for (int j = 0; j < 4; j++) acc[i][j] = {0.f, 0.f, 0.f, 0.f};

    for (int k0 = 0; k0 < K; k0 += 32) {
#pragma unroll
        for (int i = 0; i < 2; i++) {
            const int c   = tid + 256 * i;
            const int row = c >> 2, cc = c & 3;
            async_cp16(A  + (size_t)(m0 + row) * K + k0 + cc * 8,
                       (char*)As + (size_t)(wave * 64 + 256 * i) * 16);
            async_cp16(BT + (size_t)(n0 + row) * K + k0 + cc * 8,
                       (char*)Bs + (size_t)(wave * 64 + 256 * i) * 16);
        }
        __syncthreads();
        bf16x8 af[4], bfr[4];
#pragma unroll
        for (int mi = 0; mi < 4; mi++)
            af[mi] = *(const bf16x8*)(As + (wm + mi * 16 + l16) * 32 + quad * 8);
#pragma unroll
        for (int ni = 0; ni < 4; ni++)
            bfr[ni] = *(const bf16x8*)(Bs + (wn + ni * 16 + l16) * 32 + quad * 8);
#pragma unroll
        for (int mi = 0; mi < 4; mi++)
#pragma unroll
            for (int ni = 0; ni < 4; ni++)
                acc[mi][ni] = __builtin_amdgcn_mfma_f32_16x16x32_bf16(
                    af[mi], bfr[ni], acc[mi][ni], 0, 0, 0);
        __syncthreads();
    }
    // epilogue: C/D layout col=lane&15, row=quad*4+reg (m89/m91)
#pragma unroll
    for (int ni = 0; ni < 4; ni++) {
        const int col = n0 + wn + ni * 16 + l16;
        const float bv = (float)bias[col];
#pragma unroll
        for (int mi = 0; mi < 4; mi++) {
#pragma unroll
            for (int r = 0; r < 4; r++) {
                const int row = m0 + wm + mi * 16 + quad * 4 + r;
                const float val = acc[mi][ni][r] + bv;
                if (outF32) ((float*)C)[(size_t)row * N + col] = val;
                else        ((bf16*)C)[(size_t)row * N + col] = (bf16)val;
            }
        }
    }
}

// ---------------------------------------------------------------------------
// 1024x1024 transpose of a weight (f32 or bf16 source per flag) -> bf16 dst.
// ---------------------------------------------------------------------------
__global__ __launch_bounds__(256) void transpose_w(
    const void* __restrict__ src, u16* __restrict__ dst,
    const int* __restrict__ flagp)
{
    __shared__ alignas(16) u16 t[64][72];
    const bool srcF32 = (*flagp != 0);
    const int tid = threadIdx.x;
    const int r0 = blockIdx.y * 64, c0 = blockIdx.x * 64;
#pragma unroll
    for (int i = 0; i < 2; i++) {
        const int c = tid + 256 * i;
        const int r = c >> 3, ch = c & 7;
        u16x8 v;
        if (srcF32) {
            const float* sp = (const float*)src + (size_t)(r0 + r) * 1024 + c0 + ch * 8;
            const float4 a = *(const float4*)sp;
            const float4 b = *(const float4*)(sp + 4);
            bf16x8 bv;
            bv[0] = (bf16)a.x; bv[1] = (bf16)a.y; bv[2] = (bf16)a.z; bv[3] = (bf16)a.w;
            bv[4] = (bf16)b.x; bv[5] = (bf16)b.y; bv[6] = (bf16)b.z; bv[7] = (bf16)b.w;
            v = __builtin_bit_cast(u16x8, bv);
        } else {
            v = *(const u16x8*)((const u16*)src + (size_t)(r0 + r) * 1024 + c0 + ch * 8);
        }
        *(u16x8*)&t[r][ch * 8] = v;
    }
    __syncthreads();
#pragma unroll
    for (int i = 0; i < 2; i++) {
        const int c = tid + 256 * i;
        const int d = c >> 3, ch = c & 7;
        u16x8 v;
#pragma unroll
        for (int j = 0; j < 8; j++) v[j] = t[ch * 8 + j][d];
        *(u16x8*)(dst + (size_t)(c0 + d) * 1024 + r0 + ch * 8) = v;
    }
}

// ---------------------------------------------------------------------------
// Vp [b, l, h*64+d]  ->  Vt [b, h, d, l]   (bf16 ws -> bf16 ws)
// grid: (L/64, H, B)
// ---------------------------------------------------------------------------
__global__ __launch_bounds__(256) void transpose_v(
    const u16* __restrict__ Vp, u16* __restrict__ Vt)
{
    __shared__ alignas(16) u16 t[64][72];
    const int tid = threadIdx.x;
    const int l0 = blockIdx.x * 64, h = blockIdx.y, b = blockIdx.z;
    const u16* src = Vp + (size_t)(b * 1024 + l0) * 1024 + h * 64;
#pragma unroll
    for (int i = 0; i < 2; i++) {
        const int c = tid + 256 * i;
        const int l = c >> 3, ch = c & 7;
        *(u16x8*)&t[l][ch * 8] = *(const u16x8*)(src + (size_t)l * 1024 + ch * 8);
    }
    __syncthreads();
    u16* dst = Vt + ((size_t)(b * 16 + h) * 64) * 1024 + l0;
#pragma unroll
    for (int i = 0; i < 2; i++) {
        const int c = tid + 256 * i;
        const int d = c >> 3, ch = c & 7;
        u16x8 v;
#pragma unroll
        for (int j = 0; j < 8; j++) v[j] = t[ch * 8 + j][d];
        *(u16x8*)(dst + (size_t)d * 1024 + ch * 8) = v;
    }
}

// ---------------------------------------------------------------------------
// FUSED scores + softmax + PV. Per block = one (b, h, 16 q-rows).
// Phase 1: S = Q K^T * scale into LDS (f32, 64 KB).
// Phase 2: register-resident softmax (one LDS read pass); writes f32 P to
//          d_out AND bf16 P into the (dead) score buffer at stride 1032
//          (bank rotation 4 -> ~2 lanes/bank on ds_read_b128).
// Phase 3: barrier-free PV: wave w owns d-strip w*16..w*16+15, K=1024 MFMA
//          chain; V fragments read straight from L2-hot Vt slice.
// grid: (L/16, H, B)
// ---------------------------------------------------------------------------
__global__ __launch_bounds__(256) void attn_fused(
    const bf16* __restrict__ Q, const bf16* __restrict__ Kp,
    const bf16* __restrict__ Vt, bf16* __restrict__ O,
    void* __restrict__ Pout, const int* __restrict__ flagp)
{
    __shared__ alignas(16) float sc[16 * 1024];  // 64 KB; aliased as bf16 P later
    const bool outF32 = (*flagp != 0);
    const int tid  = threadIdx.x;
    const int lane = tid & 63, wave = tid >> 6;
    const int l16  = lane & 15, quad = lane >> 4;
    const int q0 = blockIdx.x * 16, h = blockIdx.y, b = blockIdx.z;

    // ---- phase 1: scores
    const bf16* Qb = Q  + (size_t)(b * 1024 + q0) * 1024 + h * 64;
    const bf16* Kb = Kp + (size_t)b * 1024 * 1024 + h * 64;
    const bf16x8 a0 = *(const bf16x8*)(Qb + (size_t)l16 * 1024 + quad * 8);
    const bf16x8 a1 = *(const bf16x8*)(Qb + (size_t)l16 * 1024 + quad * 8 + 32);
#pragma unroll 4
    for (int t = 0; t < 16; ++t) {
        const int n0 = wave * 256 + t * 16;
        const bf16* kp = Kb + (size_t)(n0 + l16) * 1024 + quad * 8;
        const bf16x8 b0 = *(const bf16x8*)kp;
        const bf16x8 b1 = *(const bf16x8*)(kp + 32);
        f32x4 acc = {0.f, 0.f, 0.f, 0.f};
        acc = __builtin_amdgcn_mfma_f32_16x16x32_bf16(a0, b0, acc, 0, 0, 0);
        acc = __builtin_amdgcn_mfma_f32_16x16x32_bf16(a1, b1, acc, 0, 0, 0);
#pragma unroll
        for (int r = 0; r < 4; r++)
            sc[(quad * 4 + r) * 1024 + n0 + l16] = acc[r] * 0.125f;
    }
    __syncthreads();

    // ---- phase 2: softmax, fully in registers (16 threads per row)
    const int r = tid >> 4, g = tid & 15;
    const float* prow = sc + r * 1024 + g * 8;
    float4 vv[16];
    float m = -3.0e38f;
#pragma unroll
    for (int j = 0; j < 8; j++) {
        vv[2 * j]     = *(const float4*)(prow + j * 128);
        vv[2 * j + 1] = *(const float4*)(prow + j * 128 + 4);
        m = fmaxf(m, fmaxf(fmaxf(vv[2 * j].x, vv[2 * j].y),
                           fmaxf(vv[2 * j].z, vv[2 * j].w)));
        m = fmaxf(m, fmaxf(fmaxf(vv[2 * j + 1].x, vv[2 * j + 1].y),
                           fmaxf(vv[2 * j + 1].z, vv[2 * j + 1].w)));
    }
#pragma unroll
    for (int o = 8; o >= 1; o >>= 1) m = fmaxf(m, __shfl_xor(m, o, 16));
    float s = 0.f;
#pragma unroll
    for (int j = 0; j < 16; j++) {
        vv[j].x = __expf(vv[j].x - m); vv[j].y = __expf(vv[j].y - m);
        vv[j].z = __expf(vv[j].z - m); vv[j].w = __expf(vv[j].w - m);
        s += vv[j].x + vv[j].y + vv[j].z + vv[j].w;
    }
#pragma unroll
    for (int o = 8; o >= 1; o >>= 1) s += __shfl_xor(s, o, 16);
    const float inv = 1.f / s;
#pragma unroll
    for (int j = 0; j < 16; j++) {
        vv[j].x *= inv; vv[j].y *= inv; vv[j].z *= inv; vv[j].w *= inv;
    }
    __syncthreads();  // all sc reads done -> safe to overwrite as bf16 P

    bf16* Pb = (bf16*)sc;  // [16][1032] padded
    const size_t rowbase = (size_t)((h * 8 + b) * 1024 + q0 + r) * 1024;
#pragma unroll
    for (int j = 0; j < 8; j++) {
        const float4 v0 = vv[2 * j], v1 = vv[2 * j + 1];
        bf16x8 ov;
        ov[0] = (bf16)v0.x; ov[1] = (bf16)v0.y; ov[2] = (bf16)v0.z; ov[3] = (bf16)v0.w;
        ov[4] = (bf16)v1.x; ov[5] = (bf16)v1.y; ov[6] = (bf16)v1.z; ov[7] = (bf16)v1.w;
        *(bf16x8*)(Pb + r * 1032 + g * 8 + j * 128) = ov;
        if (outF32) {
            float* outp = (float*)Pout + 8388608 + rowbase + g * 8 + j * 128;
            *(float4*)outp = v0;
            *(float4*)(outp + 4) = v1;
        } else {
            *(bf16x8*)((bf16*)Pout + 8388608 + rowbase + g * 8 + j * 128) = ov;
        }
    }
    __syncthreads();

    // ---- phase 3: O[16][64] = P @ V, barrier-free, per-wave 16-col strip
    const bf16* Pfrag = Pb + l16 * 1032 + quad * 8;
    const bf16* Vfrag = Vt + ((size_t)(b * 16 + h) * 64 + wave * 16 + l16) * 1024
                           + quad * 8;
    f32x4 acc0 = {0.f, 0.f, 0.f, 0.f}, acc1 = {0.f, 0.f, 0.f, 0.f};
#pragma unroll 4
    for (int k0 = 0; k0 < 1024; k0 += 64) {
        const bf16x8 pa0 = *(const bf16x8*)(Pfrag + k0);
        const bf16x8 vb0 = *(const bf16x8*)(Vfrag + k0);
        const bf16x8 pa1 = *(const bf16x8*)(Pfrag + k0 + 32);
        const bf16x8 vb1 = *(const bf16x8*)(Vfrag + k0 + 32);
        acc0 = __builtin_amdgcn_mfma_f32_16x16x32_bf16(pa0, vb0, acc0, 0, 0, 0);
        acc1 = __builtin_amdgcn_mfma_f32_16x16x32_bf16(pa1, vb1, acc1, 0, 0, 0);
    }
    bf16* Ob = O + (size_t)b * 1024 * 1024 + h * 64 + wave * 16 + l16;
#pragma unroll
    for (int rr = 0; rr < 4; rr++)
        Ob[(size_t)(q0 + quad * 4 + rr) * 1024] = (bf16)(acc0[rr] + acc1[rr]);
}

// ---------------------------------------------------------------------------
extern "C" void kernel_launch(void* const* d_in, const int* in_sizes, int n_in,
                              void* d_out, int out_size, void* d_ws, size_t ws_size,
                              hipStream_t stream)
{
    const void* q   = d_in[0];
    const void* k   = d_in[1];
    const void* v   = d_in[2];
    const void* Wq  = d_in[3];
    const void* bq  = d_in[4];
    const void* Wk  = d_in[5];
    const void* bk  = d_in[6];
    const void* Wv  = d_in[7];
    const void* bv  = d_in[8];
    const void* Wfc = d_in[9];
    const void* bfc = d_in[10];

    const size_t M1 = 1024 * 1024;
    bf16* ws   = (bf16*)d_ws;
    bf16* WqT  = ws;                  // 1M
    bf16* WkT  = ws + 1 * M1;
    bf16* WvT  = ws + 2 * M1;
    bf16* WfcT = ws + 3 * M1;
    bf16* bB   = ws + 4 * M1;         // 4 x 2048
    bf16* qb   = ws + 5 * M1;         // 8M
    bf16* kb   = ws + 13 * M1;        // 8M
    bf16* vb   = ws + 21 * M1;        // 8M
    bf16* Qp   = ws + 29 * M1;        // 8M
    bf16* Kp   = ws + 5 * M1;         // reuse qb (dead after Q-proj)
    bf16* Vp   = ws + 13 * M1;        // reuse kb (dead after K-proj)
    bf16* Vt   = ws + 21 * M1;        // reuse vb (dead after V-proj)
    bf16* O    = ws + 13 * M1;        // reuse Vp (dead after transpose_v)
    int*  flag = (int*)(ws + 37 * M1);

    const dim3 tb(256);

    detect_dtype<<<1, 64, 0, stream>>>((const u16*)q, flag);

    convert_in<<<4096, tb, 0, stream>>>(q, qb, 8 * 1024 * 1024, flag);
    convert_in<<<4096, tb, 0, stream>>>(k, kb, 8 * 1024 * 1024, flag);
    convert_in<<<4096, tb, 0, stream>>>(v, vb, 8 * 1024 * 1024, flag);
    convert_bias4<<<1, tb, 0, stream>>>(bq, bk, bv, bfc, bB, flag);

    const dim3 tg(16, 16);
    transpose_w<<<tg, tb, 0, stream>>>(Wq,  (u16*)WqT,  flag);
    transpose_w<<<tg, tb, 0, stream>>>(Wk,  (u16*)WkT,  flag);
    transpose_w<<<tg, tb, 0, stream>>>(Wv,  (u16*)WvT,  flag);
    transpose_w<<<tg, tb, 0, stream>>>(Wfc, (u16*)WfcT, flag);

    const dim3 pg(8, 64);  // N/128, M/128
    gemm_bt128<<<pg, tb, 0, stream>>>(qb, WqT, bB + 0 * 2048, Qp, 8192, 1024, 1024, nullptr);
    gemm_bt128<<<pg, tb, 0, stream>>>(kb, WkT, bB + 1 * 2048, Kp, 8192, 1024, 1024, nullptr);
    gemm_bt128<<<pg, tb, 0, stream>>>(vb, WvT, bB + 2 * 2048, Vp, 8192, 1024, 1024, nullptr);

    transpose_v<<<dim3(16, 16, 8), tb, 0, stream>>>((const u16*)Vp, (u16*)Vt);

    attn_fused<<<dim3(64, 16, 8), tb, 0, stream>>>(Qp, Kp, Vt, O, d_out, flag);

    gemm_bt128<<<pg, tb, 0, stream>>>(O, WfcT, bB + 3 * 2048, d_out, 8192, 1024, 1024, flag);
}